// Round 8
// baseline (317.731 us; speedup 1.0000x reference)
//
#include <hip/hip_runtime.h>

typedef unsigned short u16;
typedef unsigned int   u32;
typedef __attribute__((ext_vector_type(4))) float  fvec4;
typedef __attribute__((ext_vector_type(8))) __bf16 bvec8;

#define NB    64
#define SEQL  512
#define DCH   321
#define BDTOT (NB * DCH)      /* 20544 */
#define NWIN  17
#define PREDL 96
#define MWTOT (BDTOT * NWIN)  /* 349248 */
#define KPAD  1152            /* 1088 padded to 18*64 */

__device__ __forceinline__ u16 f2bf(float f) {
    union { float f; u32 u; } v; v.f = f;
    u32 r = v.u + 0x7FFFu + ((v.u >> 16) & 1u);
    return (u16)(r >> 16);
}
__device__ __forceinline__ float lrelu(float v) { return v > 0.f ? v : 0.01f * v; }

__device__ __forceinline__ void gld16(const u16* g, u16* l) {
    __builtin_amdgcn_global_load_lds((const __attribute__((address_space(1))) void*)g,
                                     (__attribute__((address_space(3))) void*)l, 16, 0, 0);
}

// ---- fused stats + normalize + transpose: x(B,SEQ,D) -> xnT(B*D,576) bf16 ----
// one kernel: pass1 reduces mean/std over SEQ, pass2 re-reads (L2-hot) + writes
// transposed normalized rows. Saves a full 42 MB HBM pass + a launch.
__global__ __launch_bounds__(256) void norm_stats_fused(
    const float* __restrict__ x, const float* __restrict__ rw,
    const float* __restrict__ rb, float* __restrict__ mean,
    float* __restrict__ stdv, u16* __restrict__ xnT) {
    __shared__ float red[2][4][64];
    __shared__ float tile[64][65];
    __shared__ float sm[64], sa[64], sb2[64];
    const int tid = threadIdx.x;
    const int i = tid & 63, j = tid >> 6;
    const int d0 = blockIdx.x * 64, b = blockIdx.y;
    const int d = d0 + i;
    const bool dok = d < DCH;
    float s = 0.f, ss = 0.f;
    if (dok) {
        for (int t = j; t < SEQL; t += 4) {
            float v = x[((size_t)b * SEQL + t) * DCH + d];
            s += v; ss += v * v;
        }
    }
    red[0][j][i] = s; red[1][j][i] = ss;
    __syncthreads();
    if (j == 0 && dok) {
        s  = red[0][0][i] + red[0][1][i] + red[0][2][i] + red[0][3][i];
        ss = red[1][0][i] + red[1][1][i] + red[1][2][i] + red[1][3][i];
        float m   = s * (1.f / SEQL);
        float var = ss * (1.f / SEQL) - m * m;
        float st  = sqrtf(var + 1e-5f);
        int bd = b * DCH + d;
        mean[bd] = m; stdv[bd] = st;
        sm[i] = m; sa[i] = rw[d] / st; sb2[i] = rb[d];
    }
    __syncthreads();
    for (int sc = 0; sc < 8; ++sc) {
        for (int e = tid; e < 4096; e += 256) {
            int sr = e >> 6, dc = e & 63;
            tile[sr][dc] = (d0 + dc < DCH)
                ? x[((size_t)b * SEQL + sc * 64 + sr) * DCH + d0 + dc] : 0.f;
        }
        __syncthreads();
        for (int e = tid; e < 4096; e += 256) {
            int dr = e >> 6, scol = e & 63;
            if (d0 + dr < DCH) {
                float v = (tile[scol][dr] - sm[dr]) * sa[dr] + sb2[dr];
                xnT[((size_t)b * DCH + d0 + dr) * 576 + 32 + sc * 64 + scol] = f2bf(v);
            }
        }
        __syncthreads();
    }
}

// merged pads: xnT halo zeros + EMB K-pad cols [1088,1152)
__global__ __launch_bounds__(256) void pads(u16* __restrict__ xnT, u16* __restrict__ EMB) {
    int idx = blockIdx.x * 256 + threadIdx.x;
    if (idx < BDTOT * 64) {
        int bd = idx >> 6, q = idx & 63;
        int off = q < 32 ? q : 512 + q;   // [0,32) front, [544,576) back
        xnT[(size_t)bd * 576 + off] = 0;
    } else if (idx < BDTOT * 64 + BDTOT * 8) {
        int t = idx - BDTOT * 64;
        int bd = t >> 3, o = (t & 7) * 8;
        fvec4 z = {0.f, 0.f, 0.f, 0.f};
        *(fvec4*)&EMB[(size_t)bd * KPAD + 1088 + o] = z;
    }
}

// -------- fold matrices: window*DFT*band-MLP layers + irfft, all precomputed --------
__global__ __launch_bounds__(256) void precompute_kernel(
    const float* __restrict__ window,
    const float* __restrict__ l0wr, const float* __restrict__ l0wi,
    const float* __restrict__ l0br, const float* __restrict__ l0bi,
    const float* __restrict__ l1wr, const float* __restrict__ l1wi,
    const float* __restrict__ l1br, const float* __restrict__ l1bi,
    const float* __restrict__ l2wr, const float* __restrict__ l2wi,
    const float* __restrict__ l2br, const float* __restrict__ l2bi,
    const float* __restrict__ m0wr, const float* __restrict__ m0wi,
    const float* __restrict__ m0br, const float* __restrict__ m0bi,
    const float* __restrict__ m1wr, const float* __restrict__ m1wi,
    const float* __restrict__ m1br, const float* __restrict__ m1bi,
    const float* __restrict__ h0wr, const float* __restrict__ h0wi,
    const float* __restrict__ h0br, const float* __restrict__ h0bi,
    u16* __restrict__ A1t, u16* __restrict__ W1t, u16* __restrict__ B2t,
    float* __restrict__ bias1, float* __restrict__ bias2, float* __restrict__ biast)
{
    int idx = blockIdx.x * 256 + threadIdx.x;
    float nrm = 0.f;
    for (int i = 0; i < 64; ++i) nrm += window[i] * window[i];
    float inv = 1.0f / sqrtf(nrm);
    const float STEP = 6.283185307179586f / 64.f;
    auto Cc = [&](int n, int k) { return  window[n] * inv * cosf(STEP * (float)((k * n) & 63)); };
    auto Ss = [&](int n, int k) { return -window[n] * inv * sinf(STEP * (float)((k * n) & 63)); };
    auto aRe = [&](int k, int n) {
        float sc = (k == 0 || k == 32) ? (1.f / 64.f) : (2.f / 64.f);
        return sc * cosf(STEP * (float)((k * n) & 63));
    };
    auto aIm = [&](int k, int n) {
        if (k == 0 || k == 32) return 0.f;            // numpy irfft ignores Im of bin0/Nyquist
        return -(2.f / 64.f) * sinf(STEP * (float)((k * n) & 63));
    };
    if (idx < 16384) {                                 // A1t [256 rows(pad)][64]
        int j = idx >> 6, n = idx & 63;
        float v = 0.f;
        if (j < 18)                    { for (int k = 0; k < 9;  ++k) v += Cc(n,k)   *l0wr[k*18+j]      - Ss(n,k)   *l0wi[k*18+j]; }
        else if (j < 36)               { int jj=j-18; for (int k = 0; k < 9;  ++k) v += Cc(n,k)   *l0wi[k*18+jj] + Ss(n,k)   *l0wr[k*18+jj]; }
        else if (j >= 64  && j < 90)   { int jj=j-64; for (int k = 0; k < 13; ++k) v += Cc(n,9+k) *m0wr[k*26+jj] - Ss(n,9+k) *m0wi[k*26+jj]; }
        else if (j >= 90  && j < 116)  { int jj=j-90; for (int k = 0; k < 13; ++k) v += Cc(n,9+k) *m0wi[k*26+jj] + Ss(n,9+k) *m0wr[k*26+jj]; }
        else if (j >= 128 && j < 139)  { int jj=j-128;for (int k = 0; k < 11; ++k) v += Cc(n,22+k)*h0wr[k*11+jj] - Ss(n,22+k)*h0wi[k*11+jj]; }
        else if (j >= 139 && j < 150)  { int jj=j-139;for (int k = 0; k < 11; ++k) v += Cc(n,22+k)*h0wi[k*11+jj] + Ss(n,22+k)*h0wr[k*11+jj]; }
        A1t[idx] = f2bf(v);
    } else if (idx < 24576) {                          // W1t [128(pad)][64]: low1 as real 36x36
        int t = idx - 16384; int j = t >> 6, k = t & 63;
        float v = 0.f;
        if (j < 18)      { if (k < 18) v = l1wr[k*18+j];        else if (k < 36) v = -l1wi[(k-18)*18+j]; }
        else if (j < 36) { int jj=j-18; if (k < 18) v = l1wi[k*18+jj]; else if (k < 36) v =  l1wr[(k-18)*18+jj]; }
        W1t[t] = f2bf(v);
    } else if (idx < 49152) {                          // B2t [128(pad)][192]: last layers + irfft
        int t = idx - 24576; int n = t / 192, c = t - n * 192;
        float v = 0.f;
        if (n < 64) {
            if (c < 18)                  { for (int m = 0; m < 9;  ++m) v +=  l2wr[c*9+m]     *aRe(m,n)   + l2wi[c*9+m]     *aIm(m,n); }
            else if (c < 36)             { int cc=c-18; for (int m = 0; m < 9;  ++m) v += -l2wi[cc*9+m]   *aRe(m,n)   + l2wr[cc*9+m]   *aIm(m,n); }
            else if (c >= 64 && c < 90)  { int cc=c-64; for (int m = 0; m < 13; ++m) v +=  m1wr[cc*13+m]  *aRe(9+m,n) + m1wi[cc*13+m]  *aIm(9+m,n); }
            else if (c >= 90 && c < 116) { int cc=c-90; for (int m = 0; m < 13; ++m) v += -m1wi[cc*13+m]  *aRe(9+m,n) + m1wr[cc*13+m]  *aIm(9+m,n); }
            else if (c >= 128 && c < 139){ v = aRe(22 + (c-128), n); }
            else if (c >= 139 && c < 150){ v = aIm(22 + (c-139), n); }
        }
        B2t[t] = f2bf(v);
    } else if (idx < 49344) {                          // bias1[192]
        int c = idx - 49152;
        float v = 0.f;
        if (c < 18) v = l0br[c];
        else if (c < 36) v = l0bi[c-18];
        else if (c >= 64 && c < 90) v = m0br[c-64];
        else if (c >= 90 && c < 116) v = m0bi[c-90];
        bias1[c] = v;
    } else if (idx < 49472) {                          // bias2[128]
        int c = idx - 49344;
        float v = 0.f;
        if (c < 18) v = l1br[c]; else if (c < 36) v = l1bi[c-18];
        bias2[c] = v;
    } else if (idx < 49536) {                          // biast[64]: all final biases thru irfft
        int n = idx - 49472;
        float v = 0.f;
        for (int k = 0; k <= 32; ++k) {
            float br = (k < 9) ? l2br[k] : (k < 22 ? m1br[k-9] : h0br[k-22]);
            float bi = (k < 9) ? l2bi[k] : (k < 22 ? m1bi[k-9] : h0bi[k-22]);
            v += aRe(k, n) * br + aIm(k, n) * bi;
        }
        biast[n] = v;
    }
}

// ---- transpose fp32 W[R][C] -> bf16 Wt[Cpad][ldw], rows rg in [R,ldw) zero-filled ----
__global__ __launch_bounds__(256) void wtrans(const float* __restrict__ W, u16* __restrict__ Wt,
                                              int R, int C, int Cpad, int ldw) {
    __shared__ float t[32][33];
    int c0 = blockIdx.x * 32, r0 = blockIdx.y * 32;
    for (int e = threadIdx.x; e < 1024; e += 256) {
        int rr = e >> 5, cc = e & 31;
        int rg = r0 + rr, cg = c0 + cc;
        t[rr][cc] = (rg < R && cg < C) ? W[(size_t)rg * C + cg] : 0.f;
    }
    __syncthreads();
    for (int e = threadIdx.x; e < 1024; e += 256) {
        int cr = e >> 5, rc = e & 31;
        int cg = c0 + cr, rg = r0 + rc;
        if (cg < Cpad && rg < ldw) Wt[(size_t)cg * ldw + rg] = f2bf(t[rc][cr]);
    }
}

// -------- fused spectral: windows -> stage1(192) -> stage2(low) -> stage3+irfft -> EMB --------
// ACT stride 200 u16 (400 B = 100 dwords, 100 mod 32 = 4): 16-row frag reads alias
// 2 lanes/bank (free, m136) instead of 4-way at the old stride 208.
__global__ __launch_bounds__(256) void spectral_fused(
    const u16* __restrict__ xnT, const u16* __restrict__ A1t,
    const u16* __restrict__ W1t, const u16* __restrict__ B2t,
    const float* __restrict__ bias1, const float* __restrict__ bias2,
    const float* __restrict__ biast, u16* __restrict__ EMB)
{
    __shared__ u16 XB[64 * 72];
    __shared__ u16 ACT[64 * 200];
    const int tid  = threadIdx.x;
    const int lane = tid & 63;
    const int wn   = tid >> 6;            // 0..3
    const int r0   = blockIdx.x * 64;

    {   // stage window rows -> XB
        int rr = tid >> 2;
        int cc = (tid & 3) * 16;
        u32 gr = (u32)(r0 + rr);
        u32 bd = gr / 17u, nw = gr - bd * 17u;
        const u16* src = xnT + (size_t)bd * 576 + nw * 32 + cc;
        *(bvec8*)&XB[rr * 72 + cc]     = *(const bvec8*)(src);
        *(bvec8*)&XB[rr * 72 + cc + 8] = *(const bvec8*)(src + 8);
    }
    __syncthreads();

    // ---- stage 1: ACT[64x192] = window @ A1^T, bias1, lrelu on cols<128 ----
    fvec4 acc1[4][3] = {};
#pragma unroll
    for (int kk = 0; kk < 2; ++kk) {
        int ko = kk * 32 + ((lane >> 4) << 3);
        bvec8 af[4], bf[3];
#pragma unroll
        for (int m = 0; m < 4; ++m)
            af[m] = *(const bvec8*)&XB[(m * 16 + (lane & 15)) * 72 + ko];
#pragma unroll
        for (int n = 0; n < 3; ++n)
            bf[n] = *(const bvec8*)(A1t + (size_t)(wn * 48 + n * 16 + (lane & 15)) * 64 + ko);
#pragma unroll
        for (int m = 0; m < 4; ++m)
#pragma unroll
            for (int n = 0; n < 3; ++n)
                acc1[m][n] = __builtin_amdgcn_mfma_f32_16x16x32_bf16(af[m], bf[n], acc1[m][n], 0, 0, 0);
    }
#pragma unroll
    for (int n = 0; n < 3; ++n) {
        int col = wn * 48 + n * 16 + (lane & 15);
        float bs = bias1[col];
#pragma unroll
        for (int m = 0; m < 4; ++m)
#pragma unroll
            for (int q = 0; q < 4; ++q) {
                int row = m * 16 + ((lane >> 4) << 2) + q;
                float v = acc1[m][n][q] + bs;
                if (col < 128) v = lrelu(v);
                ACT[row * 200 + col] = f2bf(v);
            }
    }
    __syncthreads();

    // ---- stage 2: low1 over K = cols 0..63, output cols 0..63 (in place) ----
    fvec4 acc2[4] = {};
#pragma unroll
    for (int kk = 0; kk < 2; ++kk) {
        int ko = kk * 32 + ((lane >> 4) << 3);
        bvec8 bf = *(const bvec8*)(W1t + (size_t)(wn * 16 + (lane & 15)) * 64 + ko);
#pragma unroll
        for (int m = 0; m < 4; ++m) {
            bvec8 af = *(const bvec8*)&ACT[(m * 16 + (lane & 15)) * 200 + ko];
            acc2[m] = __builtin_amdgcn_mfma_f32_16x16x32_bf16(af, bf, acc2[m], 0, 0, 0);
        }
    }
    __syncthreads();
    {
        int col = wn * 16 + (lane & 15);
        float bs = bias2[col];
#pragma unroll
        for (int m = 0; m < 4; ++m)
#pragma unroll
            for (int q = 0; q < 4; ++q) {
                int row = m * 16 + ((lane >> 4) << 2) + q;
                ACT[row * 200 + col] = f2bf(lrelu(acc2[m][q] + bs));
            }
    }
    __syncthreads();

    // ---- stage 3: EMB[64x64] = ACT[64x192] @ B2^T + biast ----
    fvec4 acc3[4] = {};
#pragma unroll
    for (int kk = 0; kk < 6; ++kk) {
        int ko = kk * 32 + ((lane >> 4) << 3);
        bvec8 bf = *(const bvec8*)(B2t + (size_t)(wn * 16 + (lane & 15)) * 192 + ko);
#pragma unroll
        for (int m = 0; m < 4; ++m) {
            bvec8 af = *(const bvec8*)&ACT[(m * 16 + (lane & 15)) * 200 + ko];
            acc3[m] = __builtin_amdgcn_mfma_f32_16x16x32_bf16(af, bf, acc3[m], 0, 0, 0);
        }
    }
    {
        int col = wn * 16 + (lane & 15);
        float bs = biast[col];
#pragma unroll
        for (int m = 0; m < 4; ++m)
#pragma unroll
            for (int q = 0; q < 4; ++q) {
                int row = m * 16 + ((lane >> 4) << 2) + q;
                int wr = r0 + row;
                int bd2 = wr / 17, nw2 = wr - bd2 * 17;
                EMB[(size_t)bd2 * KPAD + nw2 * 64 + col] = f2bf(acc3[m][q] + bs);
            }
    }
}

// ======== fc1+fc2 fused GEMM, m201 WAR-staggered pair schedule ========
// Pair (t0=2pr buf0, t1=2pr+1 buf1), 8 phases. Stage one unit/phase with 5-6
// phase prefetch depth, each write targeting a region whose old tile data was
// last read >=1 barrier earlier (WAR-safe, verified per region):
//  ph0: t1.A1  ph1: t1.B1  ph2: t2.B0  ph3: t2.A0  ph4: t2.A1  ph5: t2.B1
//  ph6: t3.B0  ph7: t3.A0      (t2=2pr+2 -> buf0, t3=2pr+3 -> buf1)
// Waits: vmcnt(4) at ph3/ph7 ends only (2 units stay in flight; induction shows
// every consumption is covered). Epilogue: H -> swizzled LDS -> fc2 mini-GEMM.
template <int SWZ>
__global__ __launch_bounds__(512, 2) void gemm_fused(
    const u16* __restrict__ A, const u16* __restrict__ Bt,
    const float* __restrict__ bias, const u16* __restrict__ W2t,
    float* __restrict__ YP,
    int Mloc, int K, long long a_off, int nwg)
{
    extern __shared__ u16 lds[];            // 2 buffers x 32768 u16 (64 KB each)
    const int tid  = threadIdx.x;
    const int lane = tid & 63;
    const int l15  = lane & 15;
    const int hi   = lane >> 4;
    const int wid  = tid >> 6;
    const int wm   = wid >> 2;
    const int wn   = wid & 3;
    int wg;
    if (SWZ) {
        int bid = blockIdx.x;
        int q = nwg >> 3, r = nwg & 7, xcd = bid & 7, off = bid >> 3;
        wg = (xcd < r) ? (xcd * (q + 1) + off) : (r * (q + 1) + (xcd - r) * q + off);
    } else wg = blockIdx.x;
    const int mt = wg >> 3;
    const int nt = wg & 7;
    const int bm0 = mt * 256, bn0 = nt * 256;

    // units: 0=A rows[0,128), 1=B k[0,32), 2=A rows[128,256), 3=B k[32,64)
    const u16* sbase[4][2];
#pragma unroll
    for (int u = 0; u < 4; ++u) {
#pragma unroll
        for (int j = 0; j < 2; ++j) {
            int idx = j * 512 + tid;
            if ((u & 1) == 0) {
                int row = (u >> 1) * 128 + (idx >> 3);
                int kc = ((idx & 7) ^ (row & 7)) << 3;
                int rl = bm0 + row; if (rl > Mloc - 1) rl = Mloc - 1;
                sbase[u][j] = A + (size_t)(a_off + rl) * K + kc;
            } else {
                int row = idx >> 2;
                int kc = (u >> 1) * 32 + (((idx & 3) ^ ((row >> 1) & 3)) << 3);
                sbase[u][j] = Bt + (size_t)(bn0 + row) * K + kc;
            }
        }
    }
    auto stage_unit = [&](int bufb, int tg, int u) {
        int base = ((u & 1) == 0) ? ((u >> 1) * 8192) : (16384 + (u >> 1) * 8192);
        u16* dstb = lds + bufb * 32768 + base;
#pragma unroll
        for (int j = 0; j < 2; ++j) {
            int idx = j * 512 + tid;
            gld16(sbase[u][j] + ((size_t)tg << 6), dstb + idx * 8);
        }
    };

    fvec4 acc[8][4] = {};
    const int NT = K >> 6;                  // 18
    const int NPAIR = NT >> 1;              // 9

    // prologue: t0 all units, t1.B0, t1.A0 (newest-2 invariant), counted wait
    stage_unit(0, 0, 0); stage_unit(0, 0, 1); stage_unit(0, 0, 2); stage_unit(0, 0, 3);
    stage_unit(1, 1, 1); stage_unit(1, 1, 0);
    asm volatile("s_waitcnt vmcnt(4)");
    __builtin_amdgcn_s_barrier();

    for (int pr = 0; pr < NPAIR; ++pr) {
        const bool hasT2 = (2 * pr + 2 < NT);
        const bool hasT3 = (2 * pr + 3 < NT);
        bvec8 bfr[4];
#pragma unroll
        for (int ph = 0; ph < 8; ++ph) {
            const int tb = ph >> 2;         // tile of pair (0 -> buf0, 1 -> buf1)
            const int p  = ph & 3;
            const int kk = p >> 1, mh = p & 1;
            const u16* Ab = lds + tb * 32768;
            const u16* Bb = Ab + 16384;
            bvec8 af[4];
            if (mh == 0) {
#pragma unroll
                for (int n = 0; n < 4; ++n) {
                    int r = wn * 64 + n * 16 + l15;
                    int ch = hi ^ ((r >> 1) & 3);
                    bfr[n] = *(const bvec8*)&Bb[kk * 8192 + r * 32 + ch * 8];
                }
            }
#pragma unroll
            for (int mm = 0; mm < 4; ++mm) {
                int r = mh * 128 + wm * 64 + mm * 16 + l15;
                int ch = (kk * 4 + hi) ^ (r & 7);
                af[mm] = *(const bvec8*)&Ab[r * 64 + ch * 8];
            }
            // WAR-staggered staging
            if (ph == 0)      stage_unit(1, 2 * pr + 1, 2);
            else if (ph == 1) stage_unit(1, 2 * pr + 1, 3);
            else if (ph == 2) { if (hasT2) stage_unit(0, 2 * pr + 2, 1); }
            else if (ph == 3) { if (hasT2) stage_unit(0, 2 * pr + 2, 0); }
            else if (ph == 4) { if (hasT2) stage_unit(0, 2 * pr + 2, 2); }
            else if (ph == 5) { if (hasT2) stage_unit(0, 2 * pr + 2, 3); }
            else if (ph == 6) { if (hasT3) stage_unit(1, 2 * pr + 3, 1); }
            else              { if (hasT3) stage_unit(1, 2 * pr + 3, 0); }
            __builtin_amdgcn_s_barrier();
            asm volatile("s_waitcnt lgkmcnt(0)");
            __builtin_amdgcn_s_setprio(1);
#pragma unroll
            for (int mm = 0; mm < 4; ++mm)
#pragma unroll
                for (int n = 0; n < 4; ++n)
                    acc[mh * 4 + mm][n] = __builtin_amdgcn_mfma_f32_16x16x32_bf16(
                        af[mm], bfr[n], acc[mh * 4 + mm][n], 0, 0, 0);
            __builtin_amdgcn_s_setprio(0);
            if (ph == 3) {
                if (hasT2) asm volatile("s_waitcnt vmcnt(4)");
                else       asm volatile("s_waitcnt vmcnt(0)");
            } else if (ph == 7) {
                if (hasT3) asm volatile("s_waitcnt vmcnt(4)");
            }
            __builtin_amdgcn_s_barrier();
        }
    }

    // ---- epilogue: H = lrelu(acc + fc1b) -> swizzled LDS (128 KB, stride 256) ----
#pragma unroll
    for (int m = 0; m < 8; ++m) {
        int mh = m >> 2, mm = m & 3;
        int row0 = mh * 128 + wm * 64 + mm * 16 + hi * 4;
#pragma unroll
        for (int n = 0; n < 4; ++n) {
            int col = wn * 64 + n * 16 + l15;
            float bs = bias[bn0 + col];
#pragma unroll
            for (int q = 0; q < 4; ++q) {
                int r = row0 + q;
                lds[r * 256 + (((col >> 3) ^ (r & 7)) << 3) + (col & 7)] =
                    f2bf(lrelu(acc[m][n][q] + bs));
            }
        }
    }
    __syncthreads();

    // ---- mini-GEMM: Yp[256x96] = H[256x256] @ W2t^T slice; wave owns 32 rows ----
    fvec4 acc2[2][6] = {};
    const int wr0 = wid * 32;
#pragma unroll
    for (int ks = 0; ks < 8; ++ks) {
        bvec8 bw[6];
#pragma unroll
        for (int cf = 0; cf < 6; ++cf)
            bw[cf] = *(const bvec8*)(W2t + (size_t)(cf * 16 + l15) * 2048 + bn0 + ks * 32 + hi * 8);
#pragma unroll
        for (int rf = 0; rf < 2; ++rf) {
            int r = wr0 + rf * 16 + l15;
            bvec8 ah = *(const bvec8*)&lds[r * 256 + (((ks * 4 + hi) ^ (r & 7)) << 3)];
#pragma unroll
            for (int cf = 0; cf < 6; ++cf)
                acc2[rf][cf] = __builtin_amdgcn_mfma_f32_16x16x32_bf16(ah, bw[cf], acc2[rf][cf], 0, 0, 0);
        }
    }
    float* yp = YP + (size_t)nt * ((size_t)BDTOT * PREDL);
#pragma unroll
    for (int rf = 0; rf < 2; ++rf) {
#pragma unroll
        for (int cf = 0; cf < 6; ++cf) {
#pragma unroll
            for (int q = 0; q < 4; ++q) {
                int r = bm0 + wr0 + rf * 16 + hi * 4 + q;
                if (r < Mloc) yp[(size_t)r * PREDL + cf * 16 + l15] = acc2[rf][cf][q];
            }
        }
    }
}

// -------- final: sum 8 fc2 partials + bias, de-norm + transpose -> out(b,p,d) --------
__global__ __launch_bounds__(256) void final_denorm(const float* __restrict__ YP,
                                                    const float* __restrict__ fc2b,
                                                    const float* __restrict__ mean,
                                                    const float* __restrict__ stdv,
                                                    const float* __restrict__ rw,
                                                    const float* __restrict__ rb,
                                                    float* __restrict__ out) {
    const size_t PART = (size_t)BDTOT * PREDL;
    __shared__ float t[32][33];
    int d0 = blockIdx.x * 32, p0 = blockIdx.y * 32, b = blockIdx.z;
    for (int e = threadIdx.x; e < 1024; e += 256) {
        int di = e >> 5, pj = e & 31;
        int d = d0 + di, p = p0 + pj;
        if (d < DCH && p < PREDL) {
            size_t off = ((size_t)b * DCH + d) * PREDL + p;
            float s = fc2b[p];
#pragma unroll
            for (int i = 0; i < 8; ++i) s += YP[off + (size_t)i * PART];
            t[di][pj] = s;
        } else t[di][pj] = 0.f;
    }
    __syncthreads();
    for (int e = threadIdx.x; e < 1024; e += 256) {
        int pi = e >> 5, dj = e & 31;
        int d = d0 + dj, p = p0 + pi;
        if (d < DCH && p < PREDL) {
            int bd = b * DCH + d;
            float v = (t[dj][pi] - rb[d]) / (rw[d] + 1e-10f) * stdv[bd] + mean[bd];
            out[((size_t)b * PREDL + p) * DCH + d] = v;
        }
    }
}

extern "C" void kernel_launch(void* const* d_in, const int* in_sizes, int n_in,
                              void* d_out, int out_size, void* d_ws, size_t ws_size,
                              hipStream_t stream) {
    const float* x      = (const float*)d_in[0];
    const float* window = (const float*)d_in[4];
    const float* rw     = (const float*)d_in[5];
    const float* rb     = (const float*)d_in[6];
    const float* l0wr = (const float*)d_in[7],  *l0wi = (const float*)d_in[8];
    const float* l0br = (const float*)d_in[9],  *l0bi = (const float*)d_in[10];
    const float* l1wr = (const float*)d_in[11], *l1wi = (const float*)d_in[12];
    const float* l1br = (const float*)d_in[13], *l1bi = (const float*)d_in[14];
    const float* l2wr = (const float*)d_in[15], *l2wi = (const float*)d_in[16];
    const float* l2br = (const float*)d_in[17], *l2bi = (const float*)d_in[18];
    const float* m0wr = (const float*)d_in[19], *m0wi = (const float*)d_in[20];
    const float* m0br = (const float*)d_in[21], *m0bi = (const float*)d_in[22];
    const float* m1wr = (const float*)d_in[23], *m1wi = (const float*)d_in[24];
    const float* m1br = (const float*)d_in[25], *m1bi = (const float*)d_in[26];
    const float* h0wr = (const float*)d_in[27], *h0wi = (const float*)d_in[28];
    const float* h0br = (const float*)d_in[29], *h0bi = (const float*)d_in[30];
    const float* fc1w = (const float*)d_in[31];
    const float* fc1b = (const float*)d_in[32];
    const float* fc2w = (const float*)d_in[33];
    const float* fc2b = (const float*)d_in[34];

    char* p = (char*)d_ws;
    auto alloc = [&](size_t n) { char* r = p; p += (n + 255) & ~(size_t)255; return r; };
    float* mean  = (float*)alloc(BDTOT * 4);
    float* stdv  = (float*)alloc(BDTOT * 4);
    float* bias1 = (float*)alloc(192 * 4);
    float* bias2 = (float*)alloc(128 * 4);
    float* biast = (float*)alloc(64 * 4);
    u16* A1t   = (u16*)alloc(256 * 64 * 2);
    u16* W1t   = (u16*)alloc(128 * 64 * 2);
    u16* B2t   = (u16*)alloc(128 * 192 * 2);
    u16* fc1wT = (u16*)alloc((size_t)2048 * KPAD * 2);
    u16* fc2wT = (u16*)alloc((size_t)128 * 2048 * 2);
    u16* xnT   = (u16*)alloc((size_t)BDTOT * 576 * 2);
    u16* EMB   = (u16*)alloc((size_t)BDTOT * KPAD * 2);
    float* YP  = (float*)alloc((size_t)8 * BDTOT * PREDL * 4);  // 8 fc2 partials

    hipFuncSetAttribute(reinterpret_cast<const void*>(&gemm_fused<1>),
                        hipFuncAttributeMaxDynamicSharedMemorySize, 131072);

    dim3 blk(256);
    norm_stats_fused<<<dim3(6, NB), blk, 0, stream>>>(x, rw, rb, mean, stdv, xnT);
    pads<<<(BDTOT * 72 + 255) / 256, blk, 0, stream>>>(xnT, EMB);
    precompute_kernel<<<194, blk, 0, stream>>>(window,
        l0wr, l0wi, l0br, l0bi, l1wr, l1wi, l1br, l1bi, l2wr, l2wi, l2br, l2bi,
        m0wr, m0wi, m0br, m0bi, m1wr, m1wi, m1br, m1bi, h0wr, h0wi, h0br, h0bi,
        A1t, W1t, B2t, bias1, bias2, biast);
    wtrans<<<dim3(64, 36), blk, 0, stream>>>(fc1w, fc1wT, 1088, 2048, 2048, KPAD);
    wtrans<<<dim3(4, 64),  blk, 0, stream>>>(fc2w, fc2wT, 2048, 96, 128, 2048);

    spectral_fused<<<MWTOT / 64, blk, 0, stream>>>(xnT, A1t, W1t, B2t, bias1, bias2, biast, EMB);

    {
        int gm = (BDTOT + 255) / 256;       // 81
        int nwg = 8 * gm;                   // 648, %8 == 0
        gemm_fused<1><<<dim3(nwg), dim3(512), 131072, stream>>>(EMB, fc1wT, fc1b, fc2wT, YP,
            BDTOT, KPAD, 0, nwg);
    }
    final_denorm<<<dim3(11, 3, NB), blk, 0, stream>>>(YP, fc2b, mean, stdv, rw, rb, (float*)d_out);
}

// Round 9
// 293.544 us; speedup vs baseline: 1.0824x; 1.0824x over previous
//
#include <hip/hip_runtime.h>

typedef unsigned short u16;
typedef unsigned int   u32;
typedef __attribute__((ext_vector_type(4))) float  fvec4;
typedef __attribute__((ext_vector_type(8))) __bf16 bvec8;

#define NB    64
#define SEQL  512
#define DCH   321
#define BDTOT (NB * DCH)      /* 20544 */
#define NWIN  17
#define PREDL 96
#define MWTOT (BDTOT * NWIN)  /* 349248 */
#define KPAD  1152            /* 1088 padded to 18*64 */

__device__ __forceinline__ u16 f2bf(float f) {
    union { float f; u32 u; } v; v.f = f;
    u32 r = v.u + 0x7FFFu + ((v.u >> 16) & 1u);
    return (u16)(r >> 16);
}
__device__ __forceinline__ float lrelu(float v) { return v > 0.f ? v : 0.01f * v; }

__device__ __forceinline__ void gld16(const u16* g, u16* l) {
    __builtin_amdgcn_global_load_lds((const __attribute__((address_space(1))) void*)g,
                                     (__attribute__((address_space(3))) void*)l, 16, 0, 0);
}

// ---------------- stats: mean / rstd / std per (b,d) over SEQ ----------------
__global__ __launch_bounds__(256) void stats_kernel(const float* __restrict__ x,
                                                    float* __restrict__ mean,
                                                    float* __restrict__ rstd,
                                                    float* __restrict__ stdv) {
    __shared__ float ls[2][4][64];
    int i = threadIdx.x & 63;
    int j = threadIdx.x >> 6;
    int bd = blockIdx.x * 64 + i;
    int b = bd / DCH, d = bd - b * DCH;
    float s = 0.f, ss = 0.f;
    for (int t = j; t < SEQL; t += 4) {
        float v = x[((size_t)b * SEQL + t) * DCH + d];
        s += v; ss += v * v;
    }
    ls[0][j][i] = s; ls[1][j][i] = ss;
    __syncthreads();
    if (j == 0) {
        s  = ls[0][0][i] + ls[0][1][i] + ls[0][2][i] + ls[0][3][i];
        ss = ls[1][0][i] + ls[1][1][i] + ls[1][2][i] + ls[1][3][i];
        float m   = s * (1.f / SEQL);
        float var = ss * (1.f / SEQL) - m * m;
        float st  = sqrtf(var + 1e-5f);
        mean[bd] = m; rstd[bd] = 1.f / st; stdv[bd] = st;
    }
}

// -------- normalize + transpose: x(B,SEQ,D) -> xnT(B*D, 576) bf16, +32 pad --------
__global__ __launch_bounds__(256) void norm_transpose(const float* __restrict__ x,
                                                      const float* __restrict__ mean,
                                                      const float* __restrict__ rstd,
                                                      const float* __restrict__ rw,
                                                      const float* __restrict__ rb,
                                                      u16* __restrict__ xnT) {
    __shared__ float tile[64][65];
    int d0 = blockIdx.x * 64, s0 = blockIdx.y * 64, b = blockIdx.z;
    for (int e = threadIdx.x; e < 4096; e += 256) {
        int sr = e >> 6, dc = e & 63;
        int d = d0 + dc;
        tile[sr][dc] = (d < DCH) ? x[((size_t)b * SEQL + s0 + sr) * DCH + d] : 0.f;
    }
    __syncthreads();
    for (int e = threadIdx.x; e < 4096; e += 256) {
        int dr = e >> 6, sc = e & 63;
        int d = d0 + dr;
        if (d < DCH) {
            int bd = b * DCH + d;
            float v = (tile[sc][dr] - mean[bd]) * rstd[bd] * rw[d] + rb[d];
            xnT[(size_t)bd * 576 + 32 + s0 + sc] = f2bf(v);
        }
    }
}

// merged pads: xnT halo zeros + EMB K-pad cols [1088,1152)
__global__ __launch_bounds__(256) void pads(u16* __restrict__ xnT, u16* __restrict__ EMB) {
    int idx = blockIdx.x * 256 + threadIdx.x;
    if (idx < BDTOT * 64) {
        int bd = idx >> 6, q = idx & 63;
        int off = q < 32 ? q : 512 + q;   // [0,32) front, [544,576) back
        xnT[(size_t)bd * 576 + off] = 0;
    } else if (idx < BDTOT * 64 + BDTOT * 8) {
        int t = idx - BDTOT * 64;
        int bd = t >> 3, o = (t & 7) * 8;
        fvec4 z = {0.f, 0.f, 0.f, 0.f};
        *(fvec4*)&EMB[(size_t)bd * KPAD + 1088 + o] = z;
    }
}

// -------- fold matrices: window*DFT*band-MLP layers + irfft, all precomputed --------
__global__ __launch_bounds__(256) void precompute_kernel(
    const float* __restrict__ window,
    const float* __restrict__ l0wr, const float* __restrict__ l0wi,
    const float* __restrict__ l0br, const float* __restrict__ l0bi,
    const float* __restrict__ l1wr, const float* __restrict__ l1wi,
    const float* __restrict__ l1br, const float* __restrict__ l1bi,
    const float* __restrict__ l2wr, const float* __restrict__ l2wi,
    const float* __restrict__ l2br, const float* __restrict__ l2bi,
    const float* __restrict__ m0wr, const float* __restrict__ m0wi,
    const float* __restrict__ m0br, const float* __restrict__ m0bi,
    const float* __restrict__ m1wr, const float* __restrict__ m1wi,
    const float* __restrict__ m1br, const float* __restrict__ m1bi,
    const float* __restrict__ h0wr, const float* __restrict__ h0wi,
    const float* __restrict__ h0br, const float* __restrict__ h0bi,
    u16* __restrict__ A1t, u16* __restrict__ W1t, u16* __restrict__ B2t,
    float* __restrict__ bias1, float* __restrict__ bias2, float* __restrict__ biast)
{
    int idx = blockIdx.x * 256 + threadIdx.x;
    float nrm = 0.f;
    for (int i = 0; i < 64; ++i) nrm += window[i] * window[i];
    float inv = 1.0f / sqrtf(nrm);
    const float STEP = 6.283185307179586f / 64.f;
    auto Cc = [&](int n, int k) { return  window[n] * inv * cosf(STEP * (float)((k * n) & 63)); };
    auto Ss = [&](int n, int k) { return -window[n] * inv * sinf(STEP * (float)((k * n) & 63)); };
    auto aRe = [&](int k, int n) {
        float sc = (k == 0 || k == 32) ? (1.f / 64.f) : (2.f / 64.f);
        return sc * cosf(STEP * (float)((k * n) & 63));
    };
    auto aIm = [&](int k, int n) {
        if (k == 0 || k == 32) return 0.f;            // numpy irfft ignores Im of bin0/Nyquist
        return -(2.f / 64.f) * sinf(STEP * (float)((k * n) & 63));
    };
    if (idx < 16384) {                                 // A1t [256 rows(pad)][64]
        int j = idx >> 6, n = idx & 63;
        float v = 0.f;
        if (j < 18)                    { for (int k = 0; k < 9;  ++k) v += Cc(n,k)   *l0wr[k*18+j]      - Ss(n,k)   *l0wi[k*18+j]; }
        else if (j < 36)               { int jj=j-18; for (int k = 0; k < 9;  ++k) v += Cc(n,k)   *l0wi[k*18+jj] + Ss(n,k)   *l0wr[k*18+jj]; }
        else if (j >= 64  && j < 90)   { int jj=j-64; for (int k = 0; k < 13; ++k) v += Cc(n,9+k) *m0wr[k*26+jj] - Ss(n,9+k) *m0wi[k*26+jj]; }
        else if (j >= 90  && j < 116)  { int jj=j-90; for (int k = 0; k < 13; ++k) v += Cc(n,9+k) *m0wi[k*26+jj] + Ss(n,9+k) *m0wr[k*26+jj]; }
        else if (j >= 128 && j < 139)  { int jj=j-128;for (int k = 0; k < 11; ++k) v += Cc(n,22+k)*h0wr[k*11+jj] - Ss(n,22+k)*h0wi[k*11+jj]; }
        else if (j >= 139 && j < 150)  { int jj=j-139;for (int k = 0; k < 11; ++k) v += Cc(n,22+k)*h0wi[k*11+jj] + Ss(n,22+k)*h0wr[k*11+jj]; }
        A1t[idx] = f2bf(v);
    } else if (idx < 24576) {                          // W1t [128(pad)][64]: low1 as real 36x36
        int t = idx - 16384; int j = t >> 6, k = t & 63;
        float v = 0.f;
        if (j < 18)      { if (k < 18) v = l1wr[k*18+j];        else if (k < 36) v = -l1wi[(k-18)*18+j]; }
        else if (j < 36) { int jj=j-18; if (k < 18) v = l1wi[k*18+jj]; else if (k < 36) v =  l1wr[(k-18)*18+jj]; }
        W1t[t] = f2bf(v);
    } else if (idx < 49152) {                          // B2t [128(pad)][192]: last layers + irfft
        int t = idx - 24576; int n = t / 192, c = t - n * 192;
        float v = 0.f;
        if (n < 64) {
            if (c < 18)                  { for (int m = 0; m < 9;  ++m) v +=  l2wr[c*9+m]     *aRe(m,n)   + l2wi[c*9+m]     *aIm(m,n); }
            else if (c < 36)             { int cc=c-18; for (int m = 0; m < 9;  ++m) v += -l2wi[cc*9+m]   *aRe(m,n)   + l2wr[cc*9+m]   *aIm(m,n); }
            else if (c >= 64 && c < 90)  { int cc=c-64; for (int m = 0; m < 13; ++m) v +=  m1wr[cc*13+m]  *aRe(9+m,n) + m1wi[cc*13+m]  *aIm(9+m,n); }
            else if (c >= 90 && c < 116) { int cc=c-90; for (int m = 0; m < 13; ++m) v += -m1wi[cc*13+m]  *aRe(9+m,n) + m1wr[cc*13+m]  *aIm(9+m,n); }
            else if (c >= 128 && c < 139){ v = aRe(22 + (c-128), n); }
            else if (c >= 139 && c < 150){ v = aIm(22 + (c-139), n); }
        }
        B2t[t] = f2bf(v);
    } else if (idx < 49344) {                          // bias1[192]
        int c = idx - 49152;
        float v = 0.f;
        if (c < 18) v = l0br[c];
        else if (c < 36) v = l0bi[c-18];
        else if (c >= 64 && c < 90) v = m0br[c-64];
        else if (c >= 90 && c < 116) v = m0bi[c-90];
        bias1[c] = v;
    } else if (idx < 49472) {                          // bias2[128]
        int c = idx - 49344;
        float v = 0.f;
        if (c < 18) v = l1br[c]; else if (c < 36) v = l1bi[c-18];
        bias2[c] = v;
    } else if (idx < 49536) {                          // biast[64]: all final biases thru irfft
        int n = idx - 49472;
        float v = 0.f;
        for (int k = 0; k <= 32; ++k) {
            float br = (k < 9) ? l2br[k] : (k < 22 ? m1br[k-9] : h0br[k-22]);
            float bi = (k < 9) ? l2bi[k] : (k < 22 ? m1bi[k-9] : h0bi[k-22]);
            v += aRe(k, n) * br + aIm(k, n) * bi;
        }
        biast[n] = v;
    }
}

// ---- transpose fp32 W[R][C] -> bf16 Wt[Cpad][ldw], rows rg in [R,ldw) zero-filled ----
__global__ __launch_bounds__(256) void wtrans(const float* __restrict__ W, u16* __restrict__ Wt,
                                              int R, int C, int Cpad, int ldw) {
    __shared__ float t[32][33];
    int c0 = blockIdx.x * 32, r0 = blockIdx.y * 32;
    for (int e = threadIdx.x; e < 1024; e += 256) {
        int rr = e >> 5, cc = e & 31;
        int rg = r0 + rr, cg = c0 + cc;
        t[rr][cc] = (rg < R && cg < C) ? W[(size_t)rg * C + cg] : 0.f;
    }
    __syncthreads();
    for (int e = threadIdx.x; e < 1024; e += 256) {
        int cr = e >> 5, rc = e & 31;
        int cg = c0 + cr, rg = r0 + rc;
        if (cg < Cpad && rg < ldw) Wt[(size_t)cg * ldw + rg] = f2bf(t[rc][cr]);
    }
}

// -------- fused spectral: windows -> stage1(192) -> stage2(low) -> stage3+irfft -> EMB --------
__global__ __launch_bounds__(256) void spectral_fused(
    const u16* __restrict__ xnT, const u16* __restrict__ A1t,
    const u16* __restrict__ W1t, const u16* __restrict__ B2t,
    const float* __restrict__ bias1, const float* __restrict__ bias2,
    const float* __restrict__ biast, u16* __restrict__ EMB)
{
    __shared__ u16 XB[64 * 72];
    __shared__ u16 ACT[64 * 200];   // stride 200: 2-lane/bank aliasing (free, m136)
    const int tid  = threadIdx.x;
    const int lane = tid & 63;
    const int wn   = tid >> 6;
    const int r0   = blockIdx.x * 64;

    {   // stage window rows -> XB
        int rr = tid >> 2;
        int cc = (tid & 3) * 16;
        u32 gr = (u32)(r0 + rr);
        u32 bd = gr / 17u, nw = gr - bd * 17u;
        const u16* src = xnT + (size_t)bd * 576 + nw * 32 + cc;
        *(bvec8*)&XB[rr * 72 + cc]     = *(const bvec8*)(src);
        *(bvec8*)&XB[rr * 72 + cc + 8] = *(const bvec8*)(src + 8);
    }
    __syncthreads();

    fvec4 acc1[4][3] = {};
#pragma unroll
    for (int kk = 0; kk < 2; ++kk) {
        int ko = kk * 32 + ((lane >> 4) << 3);
        bvec8 af[4], bf[3];
#pragma unroll
        for (int m = 0; m < 4; ++m)
            af[m] = *(const bvec8*)&XB[(m * 16 + (lane & 15)) * 72 + ko];
#pragma unroll
        for (int n = 0; n < 3; ++n)
            bf[n] = *(const bvec8*)(A1t + (size_t)(wn * 48 + n * 16 + (lane & 15)) * 64 + ko);
#pragma unroll
        for (int m = 0; m < 4; ++m)
#pragma unroll
            for (int n = 0; n < 3; ++n)
                acc1[m][n] = __builtin_amdgcn_mfma_f32_16x16x32_bf16(af[m], bf[n], acc1[m][n], 0, 0, 0);
    }
#pragma unroll
    for (int n = 0; n < 3; ++n) {
        int col = wn * 48 + n * 16 + (lane & 15);
        float bs = bias1[col];
#pragma unroll
        for (int m = 0; m < 4; ++m)
#pragma unroll
            for (int q = 0; q < 4; ++q) {
                int row = m * 16 + ((lane >> 4) << 2) + q;
                float v = acc1[m][n][q] + bs;
                if (col < 128) v = lrelu(v);
                ACT[row * 200 + col] = f2bf(v);
            }
    }
    __syncthreads();

    fvec4 acc2[4] = {};
#pragma unroll
    for (int kk = 0; kk < 2; ++kk) {
        int ko = kk * 32 + ((lane >> 4) << 3);
        bvec8 bf = *(const bvec8*)(W1t + (size_t)(wn * 16 + (lane & 15)) * 64 + ko);
#pragma unroll
        for (int m = 0; m < 4; ++m) {
            bvec8 af = *(const bvec8*)&ACT[(m * 16 + (lane & 15)) * 200 + ko];
            acc2[m] = __builtin_amdgcn_mfma_f32_16x16x32_bf16(af, bf, acc2[m], 0, 0, 0);
        }
    }
    __syncthreads();
    {
        int col = wn * 16 + (lane & 15);
        float bs = bias2[col];
#pragma unroll
        for (int m = 0; m < 4; ++m)
#pragma unroll
            for (int q = 0; q < 4; ++q) {
                int row = m * 16 + ((lane >> 4) << 2) + q;
                ACT[row * 200 + col] = f2bf(lrelu(acc2[m][q] + bs));
            }
    }
    __syncthreads();

    fvec4 acc3[4] = {};
#pragma unroll
    for (int kk = 0; kk < 6; ++kk) {
        int ko = kk * 32 + ((lane >> 4) << 3);
        bvec8 bf = *(const bvec8*)(B2t + (size_t)(wn * 16 + (lane & 15)) * 192 + ko);
#pragma unroll
        for (int m = 0; m < 4; ++m) {
            bvec8 af = *(const bvec8*)&ACT[(m * 16 + (lane & 15)) * 200 + ko];
            acc3[m] = __builtin_amdgcn_mfma_f32_16x16x32_bf16(af, bf, acc3[m], 0, 0, 0);
        }
    }
    {
        int col = wn * 16 + (lane & 15);
        float bs = biast[col];
#pragma unroll
        for (int m = 0; m < 4; ++m)
#pragma unroll
            for (int q = 0; q < 4; ++q) {
                int row = m * 16 + ((lane >> 4) << 2) + q;
                int wr = r0 + row;
                int bd2 = wr / 17, nw2 = wr - bd2 * 17;
                EMB[(size_t)bd2 * KPAD + nw2 * 64 + col] = f2bf(acc3[m][q] + bs);
            }
    }
}

// ======== fc1+fc2 fused GEMM: catalog-minimum 2-phase, ONE barrier per K-tile ========
// Per tile: STAGE(next, all 8 loads/thread) -> compute (compiler-scheduled ds_read+MFMA,
// setprio around cluster) -> __syncthreads() (implicit vmcnt(0) drains stage issued a
// full compute earlier ~= free). No sched_barrier, no inline-asm waits (m141/m230).
// T1 bijective XCD swizzle; T2 chunk-XOR LDS swizzle (inverse at global source).
// Epilogue: H -> swizzled LDS (reuses 128KB dbuf) -> fc2 mini-GEMM -> fp32 partial/nt.
template <int SWZ>
__global__ __launch_bounds__(512, 2) void gemm_fused(
    const u16* __restrict__ A, const u16* __restrict__ Bt,
    const float* __restrict__ bias, const u16* __restrict__ W2t,
    float* __restrict__ YP,
    int Mloc, int K, long long a_off, int nwg)
{
    extern __shared__ u16 lds[];            // 2 buffers x 32768 u16 (64 KB each)
    const int tid  = threadIdx.x;
    const int lane = tid & 63;
    const int l15  = lane & 15;
    const int hi   = lane >> 4;
    const int wid  = tid >> 6;
    const int wm   = wid >> 2;
    const int wn   = wid & 3;
    int wg;
    if (SWZ) {
        int bid = blockIdx.x;
        int q = nwg >> 3, r = nwg & 7, xcd = bid & 7, off = bid >> 3;
        wg = (xcd < r) ? (xcd * (q + 1) + off) : (r * (q + 1) + (xcd - r) * q + off);
    } else wg = blockIdx.x;
    const int mt = wg >> 3;
    const int nt = wg & 7;
    const int bm0 = mt * 256, bn0 = nt * 256;

    // global source bases (inverse chunk swizzle at the source, rule #21)
    const u16* sA[4];   // A: rows 0..255, idx = j*512+tid, row=idx>>3, chunk=idx&7
    const u16* sB[4];   // B: [kk][j]: row=idx>>2, chunk=idx&3 within k-half
#pragma unroll
    for (int j = 0; j < 4; ++j) {
        int idx = j * 512 + tid;
        int row = idx >> 3;
        int kc = ((idx & 7) ^ (row & 7)) << 3;
        int rl = bm0 + row; if (rl > Mloc - 1) rl = Mloc - 1;
        sA[j] = A + (size_t)(a_off + rl) * K + kc;
    }
#pragma unroll
    for (int kk = 0; kk < 2; ++kk)
#pragma unroll
        for (int j = 0; j < 2; ++j) {
            int idx = j * 512 + tid;
            int row = idx >> 2;
            int kc = kk * 32 + (((idx & 3) ^ ((row >> 1) & 3)) << 3);
            sB[kk * 2 + j] = Bt + (size_t)(bn0 + row) * K + kc;
        }

    auto stage_all = [&](int bufb, int tg) {
        u16* dst = lds + bufb * 32768;
        size_t ko = (size_t)tg << 6;
#pragma unroll
        for (int j = 0; j < 4; ++j)
            gld16(sA[j] + ko, dst + (j * 512 + tid) * 8);
#pragma unroll
        for (int kk = 0; kk < 2; ++kk)
#pragma unroll
            for (int j = 0; j < 2; ++j)
                gld16(sB[kk * 2 + j] + ko, dst + 16384 + kk * 8192 + (j * 512 + tid) * 8);
    };

    fvec4 acc[8][4] = {};
    const int NT = K >> 6;                  // 18

    stage_all(0, 0);
    __syncthreads();

    for (int t = 0; t < NT; ++t) {
        const u16* Ab = lds + (t & 1) * 32768;
        const u16* Bb = Ab + 16384;
        if (t < NT - 1) stage_all((t + 1) & 1, t + 1);
        __builtin_amdgcn_s_setprio(1);
#pragma unroll
        for (int kk = 0; kk < 2; ++kk) {
            bvec8 bfr[4], af[8];
#pragma unroll
            for (int n = 0; n < 4; ++n) {
                int r = wn * 64 + n * 16 + l15;
                int ch = hi ^ ((r >> 1) & 3);
                bfr[n] = *(const bvec8*)&Bb[kk * 8192 + r * 32 + ch * 8];
            }
#pragma unroll
            for (int m = 0; m < 8; ++m) {
                int r = (m >> 2) * 128 + wm * 64 + (m & 3) * 16 + l15;
                int ch = (kk * 4 + hi) ^ (r & 7);
                af[m] = *(const bvec8*)&Ab[r * 64 + ch * 8];
            }
#pragma unroll
            for (int m = 0; m < 8; ++m)
#pragma unroll
                for (int n = 0; n < 4; ++n)
                    acc[m][n] = __builtin_amdgcn_mfma_f32_16x16x32_bf16(
                        af[m], bfr[n], acc[m][n], 0, 0, 0);
        }
        __builtin_amdgcn_s_setprio(0);
        __syncthreads();   // implicit vmcnt(0)+lgkmcnt(0): drains next-tile stage (free)
    }

    // ---- epilogue: H = lrelu(acc + fc1b) -> swizzled LDS (128 KB, stride 256) ----
#pragma unroll
    for (int m = 0; m < 8; ++m) {
        int row0 = (m >> 2) * 128 + wm * 64 + (m & 3) * 16 + hi * 4;
#pragma unroll
        for (int n = 0; n < 4; ++n) {
            int col = wn * 64 + n * 16 + l15;
            float bs = bias[bn0 + col];
#pragma unroll
            for (int q = 0; q < 4; ++q) {
                int r = row0 + q;
                lds[r * 256 + (((col >> 3) ^ (r & 7)) << 3) + (col & 7)] =
                    f2bf(lrelu(acc[m][n][q] + bs));
            }
        }
    }
    __syncthreads();

    // ---- mini-GEMM: Yp[256x96] = H[256x256] @ W2t^T slice; wave owns 32 rows ----
    fvec4 acc2[2][6] = {};
    const int wr0 = wid * 32;
#pragma unroll
    for (int ks = 0; ks < 8; ++ks) {
        bvec8 bw[6];
#pragma unroll
        for (int cf = 0; cf < 6; ++cf)
            bw[cf] = *(const bvec8*)(W2t + (size_t)(cf * 16 + l15) * 2048 + bn0 + ks * 32 + hi * 8);
#pragma unroll
        for (int rf = 0; rf < 2; ++rf) {
            int r = wr0 + rf * 16 + l15;
            bvec8 ah = *(const bvec8*)&lds[r * 256 + (((ks * 4 + hi) ^ (r & 7)) << 3)];
#pragma unroll
            for (int cf = 0; cf < 6; ++cf)
                acc2[rf][cf] = __builtin_amdgcn_mfma_f32_16x16x32_bf16(ah, bw[cf], acc2[rf][cf], 0, 0, 0);
        }
    }
    float* yp = YP + (size_t)nt * ((size_t)BDTOT * PREDL);
#pragma unroll
    for (int rf = 0; rf < 2; ++rf) {
#pragma unroll
        for (int cf = 0; cf < 6; ++cf) {
#pragma unroll
            for (int q = 0; q < 4; ++q) {
                int r = bm0 + wr0 + rf * 16 + hi * 4 + q;
                if (r < Mloc) yp[(size_t)r * PREDL + cf * 16 + l15] = acc2[rf][cf][q];
            }
        }
    }
}

// -------- final: sum 8 fc2 partials + bias, de-norm + transpose -> out(b,p,d) --------
__global__ __launch_bounds__(256) void final_denorm(const float* __restrict__ YP,
                                                    const float* __restrict__ fc2b,
                                                    const float* __restrict__ mean,
                                                    const float* __restrict__ stdv,
                                                    const float* __restrict__ rw,
                                                    const float* __restrict__ rb,
                                                    float* __restrict__ out) {
    const size_t PART = (size_t)BDTOT * PREDL;
    __shared__ float t[32][33];
    int d0 = blockIdx.x * 32, p0 = blockIdx.y * 32, b = blockIdx.z;
    for (int e = threadIdx.x; e < 1024; e += 256) {
        int di = e >> 5, pj = e & 31;
        int d = d0 + di, p = p0 + pj;
        if (d < DCH && p < PREDL) {
            size_t off = ((size_t)b * DCH + d) * PREDL + p;
            float s = fc2b[p];
#pragma unroll
            for (int i = 0; i < 8; ++i) s += YP[off + (size_t)i * PART];
            t[di][pj] = s;
        } else t[di][pj] = 0.f;
    }
    __syncthreads();
    for (int e = threadIdx.x; e < 1024; e += 256) {
        int pi = e >> 5, dj = e & 31;
        int d = d0 + dj, p = p0 + pi;
        if (d < DCH && p < PREDL) {
            int bd = b * DCH + d;
            float v = (t[dj][pi] - rb[d]) / (rw[d] + 1e-10f) * stdv[bd] + mean[bd];
            out[((size_t)b * PREDL + p) * DCH + d] = v;
        }
    }
}

extern "C" void kernel_launch(void* const* d_in, const int* in_sizes, int n_in,
                              void* d_out, int out_size, void* d_ws, size_t ws_size,
                              hipStream_t stream) {
    const float* x      = (const float*)d_in[0];
    const float* window = (const float*)d_in[4];
    const float* rw     = (const float*)d_in[5];
    const float* rb     = (const float*)d_in[6];
    const float* l0wr = (const float*)d_in[7],  *l0wi = (const float*)d_in[8];
    const float* l0br = (const float*)d_in[9],  *l0bi = (const float*)d_in[10];
    const float* l1wr = (const float*)d_in[11], *l1wi = (const float*)d_in[12];
    const float* l1br = (const float*)d_in[13], *l1bi = (const float*)d_in[14];
    const float* l2wr = (const float*)d_in[15], *l2wi = (const float*)d_in[16];
    const float* l2br = (const float*)d_in[17], *l2bi = (const float*)d_in[18];
    const float* m0wr = (const float*)d_in[19], *m0wi = (const float*)d_in[20];
    const float* m0br = (const float*)d_in[21], *m0bi = (const float*)d_in[22];
    const float* m1wr = (const float*)d_in[23], *m1wi = (const float*)d_in[24];
    const float* m1br = (const float*)d_in[25], *m1bi = (const float*)d_in[26];
    const float* h0wr = (const float*)d_in[27], *h0wi = (const float*)d_in[28];
    const float* h0br = (const float*)d_in[29], *h0bi = (const float*)d_in[30];
    const float* fc1w = (const float*)d_in[31];
    const float* fc1b = (const float*)d_in[32];
    const float* fc2w = (const float*)d_in[33];
    const float* fc2b = (const float*)d_in[34];

    char* p = (char*)d_ws;
    auto alloc = [&](size_t n) { char* r = p; p += (n + 255) & ~(size_t)255; return r; };
    float* mean  = (float*)alloc(BDTOT * 4);
    float* rstd  = (float*)alloc(BDTOT * 4);
    float* stdv  = (float*)alloc(BDTOT * 4);
    float* bias1 = (float*)alloc(192 * 4);
    float* bias2 = (float*)alloc(128 * 4);
    float* biast = (float*)alloc(64 * 4);
    u16* A1t   = (u16*)alloc(256 * 64 * 2);
    u16* W1t   = (u16*)alloc(128 * 64 * 2);
    u16* B2t   = (u16*)alloc(128 * 192 * 2);
    u16* fc1wT = (u16*)alloc((size_t)2048 * KPAD * 2);
    u16* fc2wT = (u16*)alloc((size_t)128 * 2048 * 2);
    u16* xnT   = (u16*)alloc((size_t)BDTOT * 576 * 2);
    u16* EMB   = (u16*)alloc((size_t)BDTOT * KPAD * 2);
    float* YP  = (float*)alloc((size_t)8 * BDTOT * PREDL * 4);  // 8 fc2 partials

    hipFuncSetAttribute(reinterpret_cast<const void*>(&gemm_fused<1>),
                        hipFuncAttributeMaxDynamicSharedMemorySize, 131072);

    dim3 blk(256);
    stats_kernel<<<BDTOT / 64, blk, 0, stream>>>(x, mean, rstd, stdv);
    norm_transpose<<<dim3(6, 8, NB), blk, 0, stream>>>(x, mean, rstd, rw, rb, xnT);
    pads<<<(BDTOT * 72 + 255) / 256, blk, 0, stream>>>(xnT, EMB);
    precompute_kernel<<<194, blk, 0, stream>>>(window,
        l0wr, l0wi, l0br, l0bi, l1wr, l1wi, l1br, l1bi, l2wr, l2wi, l2br, l2bi,
        m0wr, m0wi, m0br, m0bi, m1wr, m1wi, m1br, m1bi, h0wr, h0wi, h0br, h0bi,
        A1t, W1t, B2t, bias1, bias2, biast);
    wtrans<<<dim3(64, 36), blk, 0, stream>>>(fc1w, fc1wT, 1088, 2048, 2048, KPAD);
    wtrans<<<dim3(4, 64),  blk, 0, stream>>>(fc2w, fc2wT, 2048, 96, 128, 2048);

    spectral_fused<<<MWTOT / 64, blk, 0, stream>>>(xnT, A1t, W1t, B2t, bias1, bias2, biast, EMB);

    {
        int gm = (BDTOT + 255) / 256;       // 81
        int nwg = 8 * gm;                   // 648, %8 == 0
        gemm_fused<1><<<dim3(nwg), dim3(512), 131072, stream>>>(EMB, fc1wT, fc1b, fc2wT, YP,
            BDTOT, KPAD, 0, nwg);
    }
    final_denorm<<<dim3(11, 3, NB), blk, 0, stream>>>(YP, fc2b, mean, stdv, rw, rb, (float*)d_out);
}